// Round 1
// baseline (4786.011 us; speedup 1.0000x reference)
//
#include <hip/hip_runtime.h>

// ---------------------------------------------------------------------------
// 3-layer GraphSAGE forward (mean aggregator), fp32 baseline.
//   per layer: agg[dst] += h[src] (atomics); deg[dst] += 1
//              out = h[:n_dst] @ W_self + (agg/max(deg,1)) @ W_neigh + b ; ReLU
// ---------------------------------------------------------------------------

constexpr int kN0 = 1000000;
constexpr int kN1 = 262144;
constexpr int kN2 = 32768;
constexpr int kN3 = 8192;
constexpr int kE0 = 1310720;
constexpr int kE1 = 327680;
constexpr int kE2 = 81920;

static inline unsigned cdiv_u(long long a, long long b) { return (unsigned)((a + b - 1) / b); }

// One thread per (edge, float4 chunk). D4 = row floats / 4 (25 for d=100, 64 for d=256).
template <int D4>
__global__ __launch_bounds__(256) void scatter_add(
    const int* __restrict__ src, const int* __restrict__ dst,
    const float* __restrict__ h, float* __restrict__ agg,
    float* __restrict__ deg, int nE) {
  long long t = (long long)blockIdx.x * blockDim.x + threadIdx.x;
  if (t >= (long long)nE * D4) return;
  int e = (int)(t / D4);
  int c = (int)(t - (long long)e * D4);
  int s = src[e];
  int d = dst[e];
  const float4 v = ((const float4*)(h + (long long)s * (D4 * 4)))[c];
  float* ap = agg + (long long)d * (D4 * 4) + c * 4;
  atomicAdd(ap + 0, v.x);
  atomicAdd(ap + 1, v.y);
  atomicAdd(ap + 2, v.z);
  atomicAdd(ap + 3, v.w);
  if (c == 0) atomicAdd(deg + d, 1.0f);
}

// Fused dual-GEMM + bias + (optional) ReLU + degree-normalization.
// out[i,j] = relu( Aself[i,:]·Ws[:,j] + (Agg[i,:]/max(deg,1))·Wn[:,j] + b[j] )
// Block: 256 threads; BM=16 rows staged in LDS; thread j owns output column j.
constexpr int BM = 16;

template <int K, int N, bool RELU>
__global__ __launch_bounds__(256) void sage_gemm(
    const float* __restrict__ Aself, const float* __restrict__ Agg,
    const float* __restrict__ deg,
    const float* __restrict__ Ws, const float* __restrict__ Wn,
    const float* __restrict__ bias, float* __restrict__ out) {
  __shared__ __align__(16) float s_self[BM * K];
  __shared__ __align__(16) float s_neigh[BM * K];
  __shared__ float s_scale[BM];

  const int tid = threadIdx.x;
  const long long row0 = (long long)blockIdx.x * BM;

  if (tid < BM) {
    s_scale[tid] = 1.0f / fmaxf(deg[row0 + tid], 1.0f);
  }
  __syncthreads();

  // cooperative staging of BM rows of self + normalized neigh features
  for (int idx = tid; idx < BM * K; idx += 256) {
    int r = idx / K;           // K is compile-time -> magic-mul
    int k = idx - r * K;
    s_self[idx] = Aself[(row0 + r) * K + k];
    s_neigh[idx] = Agg[(row0 + r) * K + k] * s_scale[r];
  }
  __syncthreads();

  const int j = tid;
  if (N == 256 || j < N) {
    float acc[BM];
#pragma unroll
    for (int r = 0; r < BM; ++r) acc[r] = 0.0f;

    for (int k = 0; k < K; k += 4) {
      float ws[4], wn[4];
#pragma unroll
      for (int u = 0; u < 4; ++u) {
        ws[u] = Ws[(k + u) * N + j];   // coalesced across j, L2-hot
        wn[u] = Wn[(k + u) * N + j];
      }
#pragma unroll
      for (int r = 0; r < BM; ++r) {
        const float4 a = *(const float4*)&s_self[r * K + k];   // LDS broadcast
        const float4 g = *(const float4*)&s_neigh[r * K + k];
        acc[r] += a.x * ws[0] + a.y * ws[1] + a.z * ws[2] + a.w * ws[3] +
                  g.x * wn[0] + g.y * wn[1] + g.z * wn[2] + g.w * wn[3];
      }
    }

    const float bj = bias[j];
#pragma unroll
    for (int r = 0; r < BM; ++r) {
      float v = acc[r] + bj;
      if (RELU) v = fmaxf(v, 0.0f);
      out[(row0 + r) * N + j] = v;
    }
  }
}

extern "C" void kernel_launch(void* const* d_in, const int* in_sizes, int n_in,
                              void* d_out, int out_size, void* d_ws, size_t ws_size,
                              hipStream_t stream) {
  const float* x   = (const float*)d_in[0];
  const int* es0   = (const int*)d_in[1];
  const int* ed0   = (const int*)d_in[2];
  const int* es1   = (const int*)d_in[3];
  const int* ed1   = (const int*)d_in[4];
  const int* es2   = (const int*)d_in[5];
  const int* ed2   = (const int*)d_in[6];
  const float* Ws0 = (const float*)d_in[7];
  const float* Wn0 = (const float*)d_in[8];
  const float* b0  = (const float*)d_in[9];
  const float* Ws1 = (const float*)d_in[10];
  const float* Wn1 = (const float*)d_in[11];
  const float* b1  = (const float*)d_in[12];
  const float* Ws2 = (const float*)d_in[13];
  const float* Wn2 = (const float*)d_in[14];
  const float* b2  = (const float*)d_in[15];
  float* out = (float*)d_out;

  // Workspace layout (357 MiB peak). Region A (agg0, 100 MiB) is reused for
  // all layer-1/2 buffers once the layer-0 GEMM has consumed agg0.
  char* ws = (char*)d_ws;
  float* agg0 = (float*)(ws + 0);            // N1*100*4 = 104,857,600
  float* agg1 = (float*)(ws + 0);            // N2*256*4 =  33,554,432
  float* deg1 = (float*)(ws + 33554432ull);  // N2*4     =     131,072
  float* h2   = (float*)(ws + 33685504ull);  // N2*256*4 =  33,554,432
  float* agg2 = (float*)(ws + 67239936ull);  // N3*256*4 =   8,388,608
  float* deg2 = (float*)(ws + 75628544ull);  // N3*4     =      32,768  (end 75,661,312)
  float* deg0 = (float*)(ws + 104857600ull); // N1*4     =   1,048,576
  float* h1   = (float*)(ws + 105906176ull); // N1*256*4 = 268,435,456  (end 374,341,632)

  // Zero agg0 + deg0 (contiguous span).
  hipMemsetAsync(ws, 0, 105906176ull, stream);

  // ---- layer 0: x[1M,100] -> h1[262144,256] ----
  scatter_add<25><<<cdiv_u((long long)kE0 * 25, 256), 256, 0, stream>>>(
      es0, ed0, x, agg0, deg0, kE0);
  sage_gemm<100, 256, true><<<kN1 / BM, 256, 0, stream>>>(
      x, agg0, deg0, Ws0, Wn0, b0, h1);

  // Zero agg1/deg1/agg2/deg2 (one span; also covers h2, harmless).
  hipMemsetAsync(ws, 0, 75661312ull, stream);

  // ---- layer 1: h1 -> h2[32768,256] ----
  scatter_add<64><<<cdiv_u((long long)kE1 * 64, 256), 256, 0, stream>>>(
      es1, ed1, h1, agg1, deg1, kE1);
  sage_gemm<256, 256, true><<<kN2 / BM, 256, 0, stream>>>(
      h1, agg1, deg1, Ws1, Wn1, b1, h2);

  // ---- layer 2: h2 -> out[8192,47] ----
  scatter_add<64><<<cdiv_u((long long)kE2 * 64, 256), 256, 0, stream>>>(
      es2, ed2, h2, agg2, deg2, kE2);
  sage_gemm<256, 47, false><<<kN3 / BM, 256, 0, stream>>>(
      h2, agg2, deg2, Ws2, Wn2, b2, out);
}

// Round 2
// 1742.244 us; speedup vs baseline: 2.7470x; 2.7470x over previous
//
#include <hip/hip_runtime.h>

// ---------------------------------------------------------------------------
// 3-layer GraphSAGE forward (mean aggregator), fp32.
// R1: replace float-atomic scatter with device-built CSR + gather-side mean
//     (one write per agg element, zero float atomics).
// ---------------------------------------------------------------------------

constexpr int kN0 = 1000000;
constexpr int kN1 = 262144;
constexpr int kN2 = 32768;
constexpr int kN3 = 8192;
constexpr int kE0 = 1310720;
constexpr int kE1 = 327680;
constexpr int kE2 = 81920;

static inline unsigned cdiv_u(long long a, long long b) { return (unsigned)((a + b - 1) / b); }

// ---- CSR build ----

__global__ __launch_bounds__(256) void hist_kernel(
    const int* __restrict__ dst, int* __restrict__ cnt, int nE) {
  int e = blockIdx.x * 256 + threadIdx.x;
  if (e < nE) atomicAdd(&cnt[dst[e]], 1);
}

// offsets via wave-scan + one global atomic per wave (segment order arbitrary)
__global__ __launch_bounds__(256) void offsets_kernel(
    const int* __restrict__ cnt, int* __restrict__ off, int* __restrict__ cur,
    int* __restrict__ gctr, int n) {
  int i = blockIdx.x * 256 + threadIdx.x;
  int lane = threadIdx.x & 63;
  int c = (i < n) ? cnt[i] : 0;
  int v = c;  // inclusive wave scan
#pragma unroll
  for (int d = 1; d < 64; d <<= 1) {
    int u = __shfl_up(v, d);
    if (lane >= d) v += u;
  }
  int waveTotal = __shfl(v, 63);
  int base = 0;
  if (lane == 63) base = atomicAdd(gctr, waveTotal);
  base = __shfl(base, 63);
  int excl = base + v - c;
  if (i < n) { off[i] = excl; cur[i] = excl; }
}

__global__ __launch_bounds__(256) void build_csr_kernel(
    const int* __restrict__ src, const int* __restrict__ dst,
    int* __restrict__ cur, int* __restrict__ eidx, int nE) {
  int e = blockIdx.x * 256 + threadIdx.x;
  if (e < nE) {
    int p = atomicAdd(&cur[dst[e]], 1);
    eidx[p] = src[e];
  }
}

// ---- gather-side mean: one thread per (dst, float4 chunk); fused 1/deg ----
template <int D4>
__global__ __launch_bounds__(256) void gather_mean(
    const int* __restrict__ off, const int* __restrict__ cnt,
    const int* __restrict__ eidx, const float* __restrict__ h,
    float* __restrict__ agg, int nDst) {
  long long t = (long long)blockIdx.x * 256 + threadIdx.x;
  if (t >= (long long)nDst * D4) return;
  int d = (int)(t / D4);
  int c = (int)(t - (long long)d * D4);
  int o = off[d];
  int n = cnt[d];
  float4 acc = make_float4(0.f, 0.f, 0.f, 0.f);
  for (int i = 0; i < n; ++i) {
    int s = eidx[o + i];  // same value for all chunks of this dst -> L1 hit
    float4 v = ((const float4*)(h + (long long)s * (D4 * 4)))[c];
    acc.x += v.x; acc.y += v.y; acc.z += v.z; acc.w += v.w;
  }
  float inv = 1.0f / fmaxf((float)n, 1.0f);
  acc.x *= inv; acc.y *= inv; acc.z *= inv; acc.w *= inv;
  ((float4*)(agg + (long long)d * (D4 * 4)))[c] = acc;
}

// ---- fused dual-GEMM + bias + optional ReLU (agg pre-normalized) ----
constexpr int BM = 16;

template <int K, int N, bool RELU>
__global__ __launch_bounds__(256) void sage_gemm(
    const float* __restrict__ Aself, const float* __restrict__ Agg,
    const float* __restrict__ Ws, const float* __restrict__ Wn,
    const float* __restrict__ bias, float* __restrict__ out) {
  __shared__ __align__(16) float s_self[BM * K];
  __shared__ __align__(16) float s_neigh[BM * K];

  const int tid = threadIdx.x;
  const long long row0 = (long long)blockIdx.x * BM;

  for (int idx = tid; idx < BM * K; idx += 256) {
    int r = idx / K;
    int k = idx - r * K;
    s_self[idx] = Aself[(row0 + r) * K + k];
    s_neigh[idx] = Agg[(row0 + r) * K + k];
  }
  __syncthreads();

  const int j = tid;
  if (N == 256 || j < N) {
    float acc[BM];
#pragma unroll
    for (int r = 0; r < BM; ++r) acc[r] = 0.0f;

    for (int k = 0; k < K; k += 4) {
      float ws[4], wn[4];
#pragma unroll
      for (int u = 0; u < 4; ++u) {
        ws[u] = Ws[(k + u) * N + j];
        wn[u] = Wn[(k + u) * N + j];
      }
#pragma unroll
      for (int r = 0; r < BM; ++r) {
        const float4 a = *(const float4*)&s_self[r * K + k];
        const float4 g = *(const float4*)&s_neigh[r * K + k];
        acc[r] += a.x * ws[0] + a.y * ws[1] + a.z * ws[2] + a.w * ws[3] +
                  g.x * wn[0] + g.y * wn[1] + g.z * wn[2] + g.w * wn[3];
      }
    }

    const float bj = bias[j];
#pragma unroll
    for (int r = 0; r < BM; ++r) {
      float v = acc[r] + bj;
      if (RELU) v = fmaxf(v, 0.0f);
      out[(row0 + r) * N + j] = v;
    }
  }
}

extern "C" void kernel_launch(void* const* d_in, const int* in_sizes, int n_in,
                              void* d_out, int out_size, void* d_ws, size_t ws_size,
                              hipStream_t stream) {
  const float* x   = (const float*)d_in[0];
  const int* es0   = (const int*)d_in[1];
  const int* ed0   = (const int*)d_in[2];
  const int* es1   = (const int*)d_in[3];
  const int* ed1   = (const int*)d_in[4];
  const int* es2   = (const int*)d_in[5];
  const int* ed2   = (const int*)d_in[6];
  const float* Ws0 = (const float*)d_in[7];
  const float* Wn0 = (const float*)d_in[8];
  const float* b0  = (const float*)d_in[9];
  const float* Ws1 = (const float*)d_in[10];
  const float* Wn1 = (const float*)d_in[11];
  const float* b1  = (const float*)d_in[12];
  const float* Ws2 = (const float*)d_in[13];
  const float* Wn2 = (const float*)d_in[14];
  const float* b2  = (const float*)d_in[15];
  float* out = (float*)d_out;

  // ---------------- workspace layout (lifetime-overlapped, 373.3 MB) -------
  char* ws = (char*)d_ws;
  // h1 region @0 (268,435,456 B). CSR0 lives here BEFORE gemm0 writes h1.
  float* h1   = (float*)(ws + 0);
  int* cnt0   = (int*)(ws + 0);          // 1,048,576
  int* off0   = (int*)(ws + 1048576);    // 1,048,576
  int* cur0   = (int*)(ws + 2097152);    // 1,048,576
  int* eidx0  = (int*)(ws + 3145728);    // 5,242,880 (end 8,388,608)
  // A region @268,435,456 (104,857,600 B): agg0, then layer-1 buffers.
  const size_t A = 268435456ull;
  float* agg0 = (float*)(ws + A);                  // 104,857,600
  float* agg1 = (float*)(ws + A);                  //  33,554,432
  float* h2   = (float*)(ws + A + 33554432ull);    //  33,554,432
  int* cnt1   = (int*)(ws + A + 67108864ull);      //     131,072
  int* off1   = (int*)(ws + A + 67239936ull);      //     131,072
  int* cur1   = (int*)(ws + A + 67371008ull);      //     131,072
  int* eidx1  = (int*)(ws + A + 67502080ull);      //   1,310,720 (end A+68,812,800)
  // Layer-2 buffers reuse h1 region @0 after gemm1.
  float* agg2 = (float*)(ws + 0);                  //   8,388,608
  int* cnt2   = (int*)(ws + 8388608ull);           //     131,072
  int* off2   = (int*)(ws + 8519680ull);           //     131,072
  int* cur2   = (int*)(ws + 8650752ull);           //     131,072
  int* eidx2  = (int*)(ws + 8781824ull);           //     327,680
  // global cursors (outside all regions)
  int* gctr   = (int*)(ws + 373293056ull);         //         256

  // ---- layer 0: x[1M,100] -> h1[262144,256] ----
  hipMemsetAsync(cnt0, 0, (size_t)kN1 * 4, stream);
  hipMemsetAsync(gctr, 0, 256, stream);
  hist_kernel<<<cdiv_u(kE0, 256), 256, 0, stream>>>(ed0, cnt0, kE0);
  offsets_kernel<<<cdiv_u(kN1, 256), 256, 0, stream>>>(cnt0, off0, cur0, gctr + 0, kN1);
  build_csr_kernel<<<cdiv_u(kE0, 256), 256, 0, stream>>>(es0, ed0, cur0, eidx0, kE0);
  gather_mean<25><<<cdiv_u((long long)kN1 * 25, 256), 256, 0, stream>>>(
      off0, cnt0, eidx0, x, agg0, kN1);
  sage_gemm<100, 256, true><<<kN1 / BM, 256, 0, stream>>>(
      x, agg0, Ws0, Wn0, b0, h1);

  // ---- layer 1: h1 -> h2[32768,256] ----
  hipMemsetAsync(cnt1, 0, (size_t)kN2 * 4, stream);
  hist_kernel<<<cdiv_u(kE1, 256), 256, 0, stream>>>(ed1, cnt1, kE1);
  offsets_kernel<<<cdiv_u(kN2, 256), 256, 0, stream>>>(cnt1, off1, cur1, gctr + 1, kN2);
  build_csr_kernel<<<cdiv_u(kE1, 256), 256, 0, stream>>>(es1, ed1, cur1, eidx1, kE1);
  gather_mean<64><<<cdiv_u((long long)kN2 * 64, 256), 256, 0, stream>>>(
      off1, cnt1, eidx1, h1, agg1, kN2);
  sage_gemm<256, 256, true><<<kN2 / BM, 256, 0, stream>>>(
      h1, agg1, Ws1, Wn1, b1, h2);

  // ---- layer 2: h2 -> out[8192,47] ----
  hipMemsetAsync(cnt2, 0, (size_t)kN3 * 4, stream);
  hist_kernel<<<cdiv_u(kE2, 256), 256, 0, stream>>>(ed2, cnt2, kE2);
  offsets_kernel<<<cdiv_u(kN3, 256), 256, 0, stream>>>(cnt2, off2, cur2, gctr + 2, kN3);
  build_csr_kernel<<<cdiv_u(kE2, 256), 256, 0, stream>>>(es2, ed2, cur2, eidx2, kE2);
  gather_mean<64><<<cdiv_u((long long)kN3 * 64, 256), 256, 0, stream>>>(
      off2, cnt2, eidx2, h2, agg2, kN3);
  sage_gemm<256, 47, false><<<kN3 / BM, 256, 0, stream>>>(
      h2, agg2, Ws2, Wn2, b2, out);
}

// Round 3
// 1108.271 us; speedup vs baseline: 4.3184x; 1.5720x over previous
//
#include <hip/hip_runtime.h>

// ---------------------------------------------------------------------------
// 3-layer GraphSAGE forward, R2: bf16 MFMA GEMMs (16x16x32), CSR gather-mean.
//   cat_l = [ self | neigh_mean ] in bf16 (zero-padded K halves)
//   Wt_l  = [ Wself ; Wneigh ]^T in bf16, n-major [N][Ktot]
//   out   = relu( cat @ Wt^T + b )   accumulated in fp32 via MFMA
// ---------------------------------------------------------------------------

constexpr int kN1 = 262144;
constexpr int kN2 = 32768;
constexpr int kN3 = 8192;
constexpr int kE0 = 1310720;
constexpr int kE1 = 327680;
constexpr int kE2 = 81920;

typedef __attribute__((ext_vector_type(8))) short short8;
typedef __attribute__((ext_vector_type(4))) float floatx4;

static inline unsigned cdiv_u(long long a, long long b) { return (unsigned)((a + b - 1) / b); }

__device__ __forceinline__ unsigned short f2bf(float f) {
  union { float f; unsigned u; } v; v.f = f;
  return (unsigned short)((v.u + 0x7fffu + ((v.u >> 16) & 1u)) >> 16);
}
__device__ __forceinline__ float blo(unsigned u) {
  union { unsigned u; float f; } v; v.u = u << 16; return v.f;
}
__device__ __forceinline__ float bhi(unsigned u) {
  union { unsigned u; float f; } v; v.u = u & 0xffff0000u; return v.f;
}

// ---- CSR build (unchanged from R1) ----
__global__ __launch_bounds__(256) void hist_kernel(
    const int* __restrict__ dst, int* __restrict__ cnt, int nE) {
  int e = blockIdx.x * 256 + threadIdx.x;
  if (e < nE) atomicAdd(&cnt[dst[e]], 1);
}

__global__ __launch_bounds__(256) void offsets_kernel(
    const int* __restrict__ cnt, int* __restrict__ off, int* __restrict__ cur,
    int* __restrict__ gctr, int n) {
  int i = blockIdx.x * 256 + threadIdx.x;
  int lane = threadIdx.x & 63;
  int c = (i < n) ? cnt[i] : 0;
  int v = c;
#pragma unroll
  for (int d = 1; d < 64; d <<= 1) {
    int u = __shfl_up(v, d);
    if (lane >= d) v += u;
  }
  int waveTotal = __shfl(v, 63);
  int base = 0;
  if (lane == 63) base = atomicAdd(gctr, waveTotal);
  base = __shfl(base, 63);
  int excl = base + v - c;
  if (i < n) { off[i] = excl; cur[i] = excl; }
}

__global__ __launch_bounds__(256) void build_csr_kernel(
    const int* __restrict__ src, const int* __restrict__ dst,
    int* __restrict__ cur, int* __restrict__ eidx, int nE) {
  int e = blockIdx.x * 256 + threadIdx.x;
  if (e < nE) {
    int p = atomicAdd(&cur[dst[e]], 1);
    eidx[p] = src[e];
  }
}

// ---- weight prep: Wt[n][k] bf16, [Ws rows @ k<Kself | Wn rows @ KnOff..] ----
__global__ __launch_bounds__(256) void prep_w(
    const float* __restrict__ Ws, const float* __restrict__ Wn,
    unsigned short* __restrict__ Wt, int Kself, int KnOff, int Kneigh,
    int Ktot, int Nsrc, int Ndst) {
  int t = blockIdx.x * 256 + threadIdx.x;
  if (t >= Ndst * Ktot) return;
  int n = t / Ktot, k = t - n * Ktot;
  float v = 0.f;
  if (n < Nsrc) {
    if (k < Kself) v = Ws[(size_t)k * Nsrc + n];
    else {
      int kk = k - KnOff;
      if (kk >= 0 && kk < Kneigh) v = Wn[(size_t)kk * Nsrc + n];
    }
  }
  Wt[(size_t)n * Ktot + k] = f2bf(v);
}

// ---- x fp32 [*,100] -> cat0 self half bf16 cols 0..127 (zero pad) ----
__global__ __launch_bounds__(256) void cvt_self0(
    const float* __restrict__ x, unsigned short* __restrict__ cat0, int nRows) {
  int t = blockIdx.x * 256 + threadIdx.x;
  int r = t >> 5, c = t & 31;
  if (r >= nRows) return;
  unsigned short* dst = cat0 + (size_t)r * 256 + c * 4;
  if (c >= 25) { uint2 z; z.x = 0; z.y = 0; *(uint2*)dst = z; return; }
  float4 v = *(const float4*)(x + (size_t)r * 100 + c * 4);
  uint2 pk;
  pk.x = (unsigned)f2bf(v.x) | ((unsigned)f2bf(v.y) << 16);
  pk.y = (unsigned)f2bf(v.z) | ((unsigned)f2bf(v.w) << 16);
  *(uint2*)dst = pk;
}

// ---- gather mean, fp32 source (layer 0) -> cat0 cols 128..255 ----
__global__ __launch_bounds__(256) void gather_mean0(
    const int* __restrict__ off, const int* __restrict__ cnt,
    const int* __restrict__ eidx, const float* __restrict__ x,
    unsigned short* __restrict__ cat0, int nDst) {
  int t = blockIdx.x * 256 + threadIdx.x;
  int d = t >> 5, c = t & 31;
  if (d >= nDst) return;
  unsigned short* dst = cat0 + (size_t)d * 256 + 128 + c * 4;
  if (c >= 25) { uint2 z; z.x = 0; z.y = 0; *(uint2*)dst = z; return; }
  int o = off[d], n = cnt[d];
  float ax = 0.f, ay = 0.f, az = 0.f, aw = 0.f;
  const float* xc = x + c * 4;
  for (int i = 0; i < n; ++i) {
    int s = eidx[o + i];
    float4 v = *(const float4*)(xc + (size_t)s * 100);
    ax += v.x; ay += v.y; az += v.z; aw += v.w;
  }
  float inv = 1.0f / fmaxf((float)n, 1.0f);
  uint2 pk;
  pk.x = (unsigned)f2bf(ax * inv) | ((unsigned)f2bf(ay * inv) << 16);
  pk.y = (unsigned)f2bf(az * inv) | ((unsigned)f2bf(aw * inv) << 16);
  *(uint2*)dst = pk;
}

// ---- gather mean, bf16 source [*,256] -> cat cols 256..511 ----
__global__ __launch_bounds__(256) void gather_mean_bf(
    const int* __restrict__ off, const int* __restrict__ cnt,
    const int* __restrict__ eidx, const unsigned short* __restrict__ h,
    unsigned short* __restrict__ cat, int nDst) {
  int t = blockIdx.x * 256 + threadIdx.x;
  int d = t >> 5, c = t & 31;
  if (d >= nDst) return;
  int o = off[d], n = cnt[d];
  float acc[8];
#pragma unroll
  for (int u = 0; u < 8; ++u) acc[u] = 0.f;
  const unsigned short* hc = h + c * 8;
  for (int i = 0; i < n; ++i) {
    int s = eidx[o + i];
    uint4 v = *(const uint4*)(hc + (size_t)s * 256);
    acc[0] += blo(v.x); acc[1] += bhi(v.x);
    acc[2] += blo(v.y); acc[3] += bhi(v.y);
    acc[4] += blo(v.z); acc[5] += bhi(v.z);
    acc[6] += blo(v.w); acc[7] += bhi(v.w);
  }
  float inv = 1.0f / fmaxf((float)n, 1.0f);
  uint4 pk;
  pk.x = (unsigned)f2bf(acc[0] * inv) | ((unsigned)f2bf(acc[1] * inv) << 16);
  pk.y = (unsigned)f2bf(acc[2] * inv) | ((unsigned)f2bf(acc[3] * inv) << 16);
  pk.z = (unsigned)f2bf(acc[4] * inv) | ((unsigned)f2bf(acc[5] * inv) << 16);
  pk.w = (unsigned)f2bf(acc[6] * inv) | ((unsigned)f2bf(acc[7] * inv) << 16);
  *(uint4*)(cat + (size_t)d * 512 + 256 + c * 8) = pk;
}

// ---- h [*,256] bf16 -> cat self half cols 0..255 (16B chunks) ----
__global__ __launch_bounds__(256) void copy_self(
    const unsigned short* __restrict__ h, unsigned short* __restrict__ cat, int nRows) {
  int t = blockIdx.x * 256 + threadIdx.x;
  int r = t >> 5, c = t & 31;
  if (r >= nRows) return;
  *(uint4*)(cat + (size_t)r * 512 + c * 8) = *(const uint4*)(h + (size_t)r * 256 + c * 8);
}

// ---- MFMA GEMM: C[M,256] = A[M,KT] @ Wt[256,KT]^T (+bias, relu) ----
// Block 256 = 4 waves; BM=64, BN=256 (full N). Wave w: n in [w*64, w*64+64).
// LDS rows padded 32->40 ushorts (2-way bank conflict = free).
template <int KT, bool RELU, bool OUT_BF16>
__global__ __launch_bounds__(256) void mfma_gemm(
    const unsigned short* __restrict__ A, const unsigned short* __restrict__ Wt,
    const float* __restrict__ bias, void* __restrict__ out, int nstore) {
  __shared__ __align__(16) unsigned short As[64 * 40];
  __shared__ __align__(16) unsigned short Bs[256 * 40];
  const int tid = threadIdx.x;
  const int lane = tid & 63, w = tid >> 6;
  const int q = lane >> 4, l15 = lane & 15;
  const size_t row0 = (size_t)blockIdx.x * 64;

  const int arow = tid >> 2, ak8 = (tid & 3) * 8;

  floatx4 acc[4][4];
#pragma unroll
  for (int i = 0; i < 4; ++i)
#pragma unroll
    for (int j = 0; j < 4; ++j) acc[i][j] = (floatx4){0.f, 0.f, 0.f, 0.f};

  for (int k0 = 0; k0 < KT; k0 += 32) {
    __syncthreads();
    *(uint4*)&As[arow * 40 + ak8] = *(const uint4*)&A[(row0 + arow) * KT + k0 + ak8];
#pragma unroll
    for (int it = 0; it < 4; ++it) {
      int g = tid + it * 256;
      int brow = g >> 2, bk8 = (g & 3) * 8;
      *(uint4*)&Bs[brow * 40 + bk8] = *(const uint4*)&Wt[(size_t)brow * KT + k0 + bk8];
    }
    __syncthreads();
    short8 af[4], bfv[4];
#pragma unroll
    for (int i = 0; i < 4; ++i)
      af[i] = *(const short8*)&As[(i * 16 + l15) * 40 + q * 8];
#pragma unroll
    for (int j = 0; j < 4; ++j)
      bfv[j] = *(const short8*)&Bs[(w * 64 + j * 16 + l15) * 40 + q * 8];
#pragma unroll
    for (int i = 0; i < 4; ++i)
#pragma unroll
      for (int j = 0; j < 4; ++j)
        acc[i][j] = __builtin_amdgcn_mfma_f32_16x16x32_bf16(af[i], bfv[j], acc[i][j], 0, 0, 0);
  }

  float bj[4];
#pragma unroll
  for (int j = 0; j < 4; ++j) {
    int col = w * 64 + j * 16 + l15;
    bj[j] = (col < nstore) ? bias[col] : 0.f;
  }
#pragma unroll
  for (int i = 0; i < 4; ++i) {
#pragma unroll
    for (int reg = 0; reg < 4; ++reg) {
      size_t row = row0 + i * 16 + q * 4 + reg;
#pragma unroll
      for (int j = 0; j < 4; ++j) {
        int col = w * 64 + j * 16 + l15;
        float v = acc[i][j][reg] + bj[j];
        if (RELU) v = fmaxf(v, 0.f);
        if (OUT_BF16) {
          ((unsigned short*)out)[row * 256 + col] = f2bf(v);
        } else if (col < nstore) {
          ((float*)out)[row * (size_t)nstore + col] = v;
        }
      }
    }
  }
}

extern "C" void kernel_launch(void* const* d_in, const int* in_sizes, int n_in,
                              void* d_out, int out_size, void* d_ws, size_t ws_size,
                              hipStream_t stream) {
  const float* x   = (const float*)d_in[0];
  const int* es0   = (const int*)d_in[1];
  const int* ed0   = (const int*)d_in[2];
  const int* es1   = (const int*)d_in[3];
  const int* ed1   = (const int*)d_in[4];
  const int* es2   = (const int*)d_in[5];
  const int* ed2   = (const int*)d_in[6];
  const float* Ws0 = (const float*)d_in[7];
  const float* Wn0 = (const float*)d_in[8];
  const float* b0  = (const float*)d_in[9];
  const float* Ws1 = (const float*)d_in[10];
  const float* Wn1 = (const float*)d_in[11];
  const float* b1  = (const float*)d_in[12];
  const float* Ws2 = (const float*)d_in[13];
  const float* Wn2 = (const float*)d_in[14];
  const float* b2  = (const float*)d_in[15];
  float* out = (float*)d_out;

  // ---- workspace (all disjoint, ~338 MB) ----
  char* ws = (char*)d_ws;
  unsigned short* cat0 = (unsigned short*)(ws + 0ull);          // 262144*256*2 = 134,217,728
  unsigned short* h1b  = (unsigned short*)(ws + 134217728ull);  // 134,217,728
  unsigned short* cat1 = (unsigned short*)(ws + 268435456ull);  //  33,554,432
  unsigned short* h2b  = (unsigned short*)(ws + 301989888ull);  //  16,777,216
  unsigned short* cat2 = (unsigned short*)(ws + 318767104ull);  //   8,388,608
  unsigned short* Wt0  = (unsigned short*)(ws + 327155712ull);  //     131,072
  unsigned short* Wt1  = (unsigned short*)(ws + 327286784ull);  //     262,144
  unsigned short* Wt2  = (unsigned short*)(ws + 327548928ull);  //     262,144
  int* cnt0 = (int*)(ws + 327811072ull);   // 1,048,576
  int* cnt1 = (int*)(ws + 328859648ull);   //   131,072
  int* cnt2 = (int*)(ws + 328990720ull);   //    32,768
  int* gctr = (int*)(ws + 329023488ull);   //       256
  int* off0 = (int*)(ws + 329023744ull);   // 1,048,576
  int* cur0 = (int*)(ws + 330072320ull);   // 1,048,576
  int* eidx0 = (int*)(ws + 331120896ull);  // 5,242,880
  int* off1 = (int*)(ws + 336363776ull);   //   131,072
  int* cur1 = (int*)(ws + 336494848ull);   //   131,072
  int* eidx1 = (int*)(ws + 336625920ull);  // 1,310,720
  int* off2 = (int*)(ws + 337936640ull);   //    32,768
  int* cur2 = (int*)(ws + 337969408ull);   //    32,768
  int* eidx2 = (int*)(ws + 338002176ull);  //   327,680

  // zero all cnt + gctr in one contiguous span [327811072, 329023744+256)
  hipMemsetAsync(ws + 327811072ull, 0, 1212928ull, stream);

  // ---- CSR builds (independent of features) ----
  hist_kernel<<<cdiv_u(kE0, 256), 256, 0, stream>>>(ed0, cnt0, kE0);
  hist_kernel<<<cdiv_u(kE1, 256), 256, 0, stream>>>(ed1, cnt1, kE1);
  hist_kernel<<<cdiv_u(kE2, 256), 256, 0, stream>>>(ed2, cnt2, kE2);
  offsets_kernel<<<cdiv_u(kN1, 256), 256, 0, stream>>>(cnt0, off0, cur0, gctr + 0, kN1);
  offsets_kernel<<<cdiv_u(kN2, 256), 256, 0, stream>>>(cnt1, off1, cur1, gctr + 1, kN2);
  offsets_kernel<<<cdiv_u(kN3, 256), 256, 0, stream>>>(cnt2, off2, cur2, gctr + 2, kN3);
  build_csr_kernel<<<cdiv_u(kE0, 256), 256, 0, stream>>>(es0, ed0, cur0, eidx0, kE0);
  build_csr_kernel<<<cdiv_u(kE1, 256), 256, 0, stream>>>(es1, ed1, cur1, eidx1, kE1);
  build_csr_kernel<<<cdiv_u(kE2, 256), 256, 0, stream>>>(es2, ed2, cur2, eidx2, kE2);

  // ---- weight prep ----
  prep_w<<<cdiv_u(256 * 256, 256), 256, 0, stream>>>(Ws0, Wn0, Wt0, 100, 128, 100, 256, 256, 256);
  prep_w<<<cdiv_u(256 * 512, 256), 256, 0, stream>>>(Ws1, Wn1, Wt1, 256, 256, 256, 512, 256, 256);
  prep_w<<<cdiv_u(256 * 512, 256), 256, 0, stream>>>(Ws2, Wn2, Wt2, 256, 256, 256, 512, 47, 256);

  // ---- layer 0 ----
  cvt_self0<<<cdiv_u((long long)kN1 * 32, 256), 256, 0, stream>>>(x, cat0, kN1);
  gather_mean0<<<cdiv_u((long long)kN1 * 32, 256), 256, 0, stream>>>(
      off0, cnt0, eidx0, x, cat0, kN1);
  mfma_gemm<256, true, true><<<kN1 / 64, 256, 0, stream>>>(cat0, Wt0, b0, h1b, 256);

  // ---- layer 1 ----
  copy_self<<<cdiv_u((long long)kN2 * 32, 256), 256, 0, stream>>>(h1b, cat1, kN2);
  gather_mean_bf<<<cdiv_u((long long)kN2 * 32, 256), 256, 0, stream>>>(
      off1, cnt1, eidx1, h1b, cat1, kN2);
  mfma_gemm<512, true, true><<<kN2 / 64, 256, 0, stream>>>(cat1, Wt1, b1, h2b, 256);

  // ---- layer 2 ----
  copy_self<<<cdiv_u((long long)kN3 * 32, 256), 256, 0, stream>>>(h2b, cat2, kN3);
  gather_mean_bf<<<cdiv_u((long long)kN3 * 32, 256), 256, 0, stream>>>(
      off2, cnt2, eidx2, h2b, cat2, kN3);
  mfma_gemm<512, false, false><<<kN3 / 64, 256, 0, stream>>>(cat2, Wt2, b2, out, 47);
}